// Round 1
// baseline (188.318 us; speedup 1.0000x reference)
//
#include <hip/hip_runtime.h>

#define NA   128   // batches
#define NPTS 256   // points per path
#define DD   16    // feature dim
#define MMI  255   // increments per axis (NPTS-1)

// One wave (64 lanes) per (pair, batch) problem. Lane l owns inc-columns
// 4l..4l+3. Skewed wavefront: at step s, lane l processes inc-row r = s - l.
// Neighbor boundary values passed via __shfl_up (no barriers in main loop).
__global__ __launch_bounds__(64)
void sig_pde(const float* __restrict__ X, const float* __restrict__ Y,
             float* __restrict__ out) {
    const int pid  = blockIdx.x;
    const int pair = pid >> 7;     // 0: XX, 1: YY, 2: XY
    const int a    = pid & 127;
    const float* U = (pair == 1) ? Y : X;
    const float* V = (pair == 0) ? X : Y;
    const float  w = (pair == 2) ? (-2.0f / (float)NA) : (1.0f / (float)NA);
    U += (size_t)a * (NPTS * DD);
    V += (size_t)a * (NPTS * DD);

    // dU in transposed-quad layout: dU[qd][r][0..3] = channels 4qd..4qd+3 of
    // increment row r. Main-loop read: 4x ds_read_b128, lanes at consecutive r
    // -> contiguous 16B-strided addresses -> conflict-free.
    __shared__ float dU[4][256][4];

    const int lane = threadIdx.x;

    // ---- stage dU = diff(U) into LDS ----
    const float4* U4 = (const float4*)U;
    for (int i = 0; i < 16; ++i) {
        int t  = lane + (i << 6);          // 0..1023
        int qd = t >> 8;
        int r  = t & 255;
        if (r < MMI) {
            float4 lo = U4[r * 4 + qd];
            float4 hi = U4[r * 4 + 4 + qd];
            *(float4*)(&dU[qd][r][0]) =
                make_float4(hi.x - lo.x, hi.y - lo.y, hi.z - lo.z, hi.w - lo.w);
        }
    }

    // ---- dV for this lane's 4 columns, in registers (zero-pad col 255) ----
    float4 v[4][4];
    #pragma unroll
    for (int k = 0; k < 4; ++k) {
        int j = (lane << 2) + k;
        if (j < MMI) {
            const float4* Va = (const float4*)(V + (size_t)j * DD);
            const float4* Vb = (const float4*)(V + (size_t)(j + 1) * DD);
            #pragma unroll
            for (int q = 0; q < 4; ++q) {
                float4 lo = Va[q], hi = Vb[q];
                v[k][q] = make_float4(hi.x - lo.x, hi.y - lo.y,
                                      hi.z - lo.z, hi.w - lo.w);
            }
        } else {
            #pragma unroll
            for (int q = 0; q < 4; ++q) v[k][q] = make_float4(0.f, 0.f, 0.f, 0.f);
        }
    }

    __syncthreads();

    // K-grid state for this lane's columns j = 4l+1 .. 4l+4:
    // kup[k] = K[r+1][4l+k+1] after processing row r.
    float kup[4] = {1.f, 1.f, 1.f, 1.f};
    float k3old  = 1.f;   // kup[3] as of two steps ago (for the up-left value)

    for (int s = 0; s < MMI + 63; ++s) {
        // from left neighbor: K[r+1][4l] (left) and K[r][4l] (up-left)
        float sh_new = __shfl_up(kup[3], 1);
        float sh_old = __shfl_up(k3old, 1);
        if (lane == 0) { sh_new = 1.f; sh_old = 1.f; }  // K[*][0] = 1
        k3old = kup[3];

        const int r = s - lane;
        if (0 <= r && r < MMI) {
            const float4 u0 = *(const float4*)(&dU[0][r][0]);
            const float4 u1 = *(const float4*)(&dU[1][r][0]);
            const float4 u2 = *(const float4*)(&dU[2][r][0]);
            const float4 u3 = *(const float4*)(&dU[3][r][0]);

            float c1[4], c2[4];
            #pragma unroll
            for (int k = 0; k < 4; ++k) {
                float g =
                    u0.x * v[k][0].x + u0.y * v[k][0].y + u0.z * v[k][0].z + u0.w * v[k][0].w +
                    u1.x * v[k][1].x + u1.y * v[k][1].y + u1.z * v[k][1].z + u1.w * v[k][1].w +
                    u2.x * v[k][2].x + u2.y * v[k][2].y + u2.z * v[k][2].z + u2.w * v[k][2].w +
                    u3.x * v[k][3].x + u3.y * v[k][3].y + u3.z * v[k][3].z + u3.w * v[k][3].w;
                float e = g * g * (1.0f / 12.0f);
                c1[k] = 1.0f + 0.5f * g + e;   // 1 + g/2 + g^2/12
                c2[k] = 1.0f - e;              // 1 - g^2/12
            }

            float kleft = sh_new;
            float kdiag = sh_old;
            #pragma unroll
            for (int k = 0; k < 4; ++k) {
                float t = (kleft + kup[k]) * c1[k] - kdiag * c2[k];
                kdiag = kup[k];
                kup[k] = t;
                kleft = t;
            }
        }
    }

    // K[255][255] lives in lane 63's kup[2] (j = 4*63+2+1 = 255)
    if (lane == 63) atomicAdd(out, w * kup[2]);
}

extern "C" void kernel_launch(void* const* d_in, const int* in_sizes, int n_in,
                              void* d_out, int out_size, void* d_ws, size_t ws_size,
                              hipStream_t stream) {
    const float* X = (const float*)d_in[0];
    const float* Y = (const float*)d_in[1];
    float* out = (float*)d_out;
    // harness poisons d_out before every timed launch; we accumulate atomically
    hipMemsetAsync(out, 0, sizeof(float), stream);
    sig_pde<<<dim3(3 * NA), dim3(64), 0, stream>>>(X, Y, out);
}

// Round 2
// 121.276 us; speedup vs baseline: 1.5528x; 1.5528x over previous
//
#include <hip/hip_runtime.h>

#define NA   128   // batches
#define NPTS 256   // points per path
#define DD   16    // feature dim
#define MMI  255   // increments per axis (NPTS-1)

__device__ __forceinline__ float2 pkfma(float2 a, float2 b, float2 c) {
    return make_float2(fmaf(a.x, b.x, c.x), fmaf(a.y, b.y, c.y));
}

// One wave (64 lanes) per (pair, batch) problem. Lane l owns inc-columns
// 4l..4l+3. Skewed wavefront: at step s, lane l processes inc-row r = s - l.
// Single __shfl_up per step (up-left = previous step's shuffle result);
// recurrence rewritten as t = fma(left, c1, pre) so the cross-lane critical
// path is 4 chained FMAs; next row's coefficients computed under the
// bpermute/ds_read latency.
__global__ __launch_bounds__(64)
void sig_pde(const float* __restrict__ X, const float* __restrict__ Y,
             float* __restrict__ out) {
    const int pid  = blockIdx.x;
    const int pair = pid >> 7;     // 0: XX, 1: YY, 2: XY
    const int a    = pid & 127;
    const float* U = (pair == 1) ? Y : X;
    const float* V = (pair == 0) ? X : Y;
    const float  w = (pair == 2) ? (-2.0f / (float)NA) : (1.0f / (float)NA);
    U += (size_t)a * (NPTS * DD);
    V += (size_t)a * (NPTS * DD);

    // dU[qd][r][0..3] = channels 4qd..4qd+3 of increment row r.
    // Per-step read: 4x ds_read_b128, lanes at consecutive r -> conflict-free.
    __shared__ float dU[4][256][4];

    const int lane = threadIdx.x;

    // ---- stage dU = diff(U) into LDS ----
    const float4* U4 = (const float4*)U;
    for (int i = 0; i < 16; ++i) {
        int t  = lane + (i << 6);          // 0..1023
        int qd = t >> 8;
        int r  = t & 255;
        if (r < MMI) {
            float4 lo = U4[r * 4 + qd];
            float4 hi = U4[r * 4 + 4 + qd];
            *(float4*)(&dU[qd][r][0]) =
                make_float4(hi.x - lo.x, hi.y - lo.y, hi.z - lo.z, hi.w - lo.w);
        }
    }

    // ---- dV for this lane's 4 columns, registers (zero for col >= 255) ----
    float2 v[4][8];
    #pragma unroll
    for (int k = 0; k < 4; ++k) {
        int j = (lane << 2) + k;
        const bool valid = (j < MMI);
        const int jj = valid ? j : 0;
        const float2* Va = (const float2*)(V + (size_t)jj * DD);
        const float2* Vb = (const float2*)(V + (size_t)(jj + 1) * DD);
        #pragma unroll
        for (int q = 0; q < 8; ++q) {
            float2 lo = Va[q], hi = Vb[q];
            v[k][q] = valid ? make_float2(hi.x - lo.x, hi.y - lo.y)
                            : make_float2(0.f, 0.f);
        }
    }

    __syncthreads();

    // kup[k] = K[r+1][4l+k+1] after processing row r
    float kup[4] = {1.f, 1.f, 1.f, 1.f};
    float shnew = 1.f;    // shuffle result for the upcoming step (left value)
    float shprev = 1.f;   // shuffle result from the previous step (up-left)
    float c1[4], c2[4];   // coefficients for the current step's row

    // coefficients for clamped row rc (valid rows only matter for active lanes)
    auto compute_c = [&](int rc) {
        const float4 u0 = *(const float4*)(&dU[0][rc][0]);
        const float4 u1 = *(const float4*)(&dU[1][rc][0]);
        const float4 u2 = *(const float4*)(&dU[2][rc][0]);
        const float4 u3 = *(const float4*)(&dU[3][rc][0]);
        const float2 uu[8] = {
            make_float2(u0.x, u0.y), make_float2(u0.z, u0.w),
            make_float2(u1.x, u1.y), make_float2(u1.z, u1.w),
            make_float2(u2.x, u2.y), make_float2(u2.z, u2.w),
            make_float2(u3.x, u3.y), make_float2(u3.z, u3.w)};
        #pragma unroll
        for (int k = 0; k < 4; ++k) {
            float2 acc = make_float2(0.f, 0.f);
            #pragma unroll
            for (int q = 0; q < 8; ++q) acc = pkfma(uu[q], v[k][q], acc);
            const float g = acc.x + acc.y;
            const float e = g * g * (1.0f / 12.0f);
            c1[k] = fmaf(0.5f, g, 1.0f) + e;   // 1 + g/2 + g^2/12
            c2[k] = 1.0f - e;                  // 1 - g^2/12
        }
    };

    compute_c(0);   // row for step 0 (only lane 0 is active there)

    for (int s = 0; s < MMI + 63; ++s) {
        const int r = s - lane;
        const bool active = ((unsigned)r < (unsigned)MMI);

        const float left   = (lane == 0) ? 1.f : shnew;
        const float upleft = (lane == 0) ? 1.f : shprev;

        // pre[k] = kup[k]*c1[k] - kdiag[k]*c2[k]  (independent of `left`)
        const float pre0 = fmaf(kup[0], c1[0], -(upleft * c2[0]));
        const float pre1 = fmaf(kup[1], c1[1], -(kup[0] * c2[1]));
        const float pre2 = fmaf(kup[2], c1[2], -(kup[1] * c2[2]));
        const float pre3 = fmaf(kup[3], c1[3], -(kup[2] * c2[3]));

        // serial chain: 4 FMAs
        const float t0 = fmaf(left, c1[0], pre0);
        const float t1 = fmaf(t0,   c1[1], pre1);
        const float t2 = fmaf(t1,   c1[2], pre2);
        const float t3 = fmaf(t2,   c1[3], pre3);

        shprev = shnew;
        kup[0] = active ? t0 : kup[0];
        kup[1] = active ? t1 : kup[1];
        kup[2] = active ? t2 : kup[2];
        kup[3] = active ? t3 : kup[3];

        // issue the cross-lane shuffle for the next step, then hide its
        // latency under next-row coefficient computation
        shnew = __shfl_up(kup[3], 1);

        int rn = r + 1;
        rn = (rn < 0) ? 0 : (rn > MMI - 1 ? MMI - 1 : rn);
        compute_c(rn);
    }

    // K[255][255] lives in lane 63's kup[2] (j = 4*63+2+1 = 255)
    if (lane == 63) atomicAdd(out, w * kup[2]);
}

extern "C" void kernel_launch(void* const* d_in, const int* in_sizes, int n_in,
                              void* d_out, int out_size, void* d_ws, size_t ws_size,
                              hipStream_t stream) {
    const float* X = (const float*)d_in[0];
    const float* Y = (const float*)d_in[1];
    float* out = (float*)d_out;
    hipMemsetAsync(out, 0, sizeof(float), stream);
    sig_pde<<<dim3(3 * NA), dim3(64), 0, stream>>>(X, Y, out);
}

// Round 3
// 115.605 us; speedup vs baseline: 1.6290x; 1.0491x over previous
//
#include <hip/hip_runtime.h>

typedef float f32x2 __attribute__((ext_vector_type(2)));

#define NA   128   // batches
#define NPTS 256   // points per path
#define DD   16    // feature dim
#define MMI  255   // increments per axis (NPTS-1)

// whole-wave shift-down-by-1 via DPP (lane l gets lane l-1's value).
// Lane 0 (invalid source, bound_ctrl=0) keeps `old` = boundary value.
__device__ __forceinline__ float wave_shr1(float x, float boundary) {
    int r = __builtin_amdgcn_update_dpp(
        __builtin_bit_cast(int, boundary),
        __builtin_bit_cast(int, x),
        0x138 /* wave_shr:1 */, 0xF, 0xF, false);
    return __builtin_bit_cast(float, r);
}

// One wave (64 lanes) per (pair, batch) problem. Lane l owns inc-columns
// 4l..4l+3. Skewed wavefront: at step s, lane l processes inc-row r = s - l.
// Cross-lane hop is a DPP wave_shr (VALU, ~4cy) -> no LDS op on the
// loop-carried critical path. Row data double-buffered one step ahead.
__global__ __launch_bounds__(64)
void sig_pde(const float* __restrict__ X, const float* __restrict__ Y,
             float* __restrict__ out) {
    const int pid  = blockIdx.x;
    const int pair = pid >> 7;     // 0: XX, 1: YY, 2: XY
    const int a    = pid & 127;
    const float* U = (pair == 1) ? Y : X;
    const float* V = (pair == 0) ? X : Y;
    const float  w = (pair == 2) ? (-2.0f / (float)NA) : (1.0f / (float)NA);
    U += (size_t)a * (NPTS * DD);
    V += (size_t)a * (NPTS * DD);

    // dU[qd][r][0..3] = channels 4qd..4qd+3 of increment row r.
    __shared__ float dU[4][256][4];

    const int lane = threadIdx.x;

    // ---- stage dU = diff(U) into LDS ----
    const float4* U4 = (const float4*)U;
    for (int i = 0; i < 16; ++i) {
        int t  = lane + (i << 6);          // 0..1023
        int qd = t >> 8;
        int r  = t & 255;
        if (r < MMI) {
            float4 lo = U4[r * 4 + qd];
            float4 hi = U4[r * 4 + 4 + qd];
            *(float4*)(&dU[qd][r][0]) =
                make_float4(hi.x - lo.x, hi.y - lo.y, hi.z - lo.z, hi.w - lo.w);
        }
    }

    // ---- dV for this lane's 4 columns, registers (zero for col >= 255) ----
    f32x2 v[4][8];
    #pragma unroll
    for (int k = 0; k < 4; ++k) {
        int j = (lane << 2) + k;
        const bool valid = (j < MMI);
        const int jj = valid ? j : 0;
        const float2* Va = (const float2*)(V + (size_t)jj * DD);
        const float2* Vb = (const float2*)(V + (size_t)(jj + 1) * DD);
        #pragma unroll
        for (int q = 0; q < 8; ++q) {
            float2 lo = Va[q], hi = Vb[q];
            v[k][q] = valid ? f32x2{hi.x - lo.x, hi.y - lo.y} : f32x2{0.f, 0.f};
        }
    }

    __syncthreads();

    auto load_row = [&](int rc, f32x2* uu) {
        #pragma unroll
        for (int q = 0; q < 4; ++q) {
            float4 t = *(const float4*)(&dU[q][rc][0]);
            uu[2 * q + 0] = f32x2{t.x, t.y};
            uu[2 * q + 1] = f32x2{t.z, t.w};
        }
    };

    float c1[4], c2[4];
    auto compute_c = [&](const f32x2* uu) {
        #pragma unroll
        for (int k = 0; k < 4; ++k) {
            f32x2 acc = uu[0] * v[k][0];
            #pragma unroll
            for (int q = 1; q < 8; ++q) acc += uu[q] * v[k][q];  // v_pk_fma_f32
            const float g = acc.x + acc.y;
            const float e = g * g * (1.0f / 12.0f);
            c1[k] = fmaf(0.5f, g, 1.0f) + e;   // 1 + g/2 + g^2/12
            c2[k] = 1.0f - e;                  // 1 - g^2/12
        }
    };

    // pipeline init: c holds row-0 coeffs (used first at step s=lane, r=0);
    // un holds the row consumed by compute_c at s=0: row clamp(1-lane).
    {
        f32x2 uu[8];
        load_row(0, uu);
        compute_c(uu);
    }
    f32x2 un[8];
    {
        int r1 = 1 - lane;
        r1 = (r1 < 0) ? 0 : r1;
        load_row(r1, un);
    }

    // kup[k] = K[r+1][4l+k+1] after processing row r
    float kup[4] = {1.f, 1.f, 1.f, 1.f};
    float shnew  = 1.f;   // left value for the upcoming step
    float shprev = 1.f;   // up-left value (previous step's shuffle)

    #pragma unroll 2
    for (int s = 0; s < MMI + 63; ++s) {
        const int r = s - lane;
        const bool active = ((unsigned)r < (unsigned)MMI);

        const float left   = shnew;
        const float upleft = shprev;

        // pre[k] = kup[k]*c1[k] - kdiag[k]*c2[k]  (independent of `left`)
        const float pre0 = fmaf(kup[0], c1[0], -(upleft * c2[0]));
        const float pre1 = fmaf(kup[1], c1[1], -(kup[0] * c2[1]));
        const float pre2 = fmaf(kup[2], c1[2], -(kup[1] * c2[2]));
        const float pre3 = fmaf(kup[3], c1[3], -(kup[2] * c2[3]));

        // serial chain: 4 FMAs
        const float t0 = fmaf(left, c1[0], pre0);
        const float t1 = fmaf(t0,   c1[1], pre1);
        const float t2 = fmaf(t1,   c1[2], pre2);
        const float t3 = fmaf(t2,   c1[3], pre3);

        shprev = shnew;
        kup[0] = active ? t0 : kup[0];
        kup[1] = active ? t1 : kup[1];
        kup[2] = active ? t2 : kup[2];
        kup[3] = active ? t3 : kup[3];

        // cross-lane hop: VALU DPP, lane0 gets boundary 1.0
        shnew = wave_shr1(kup[3], 1.0f);

        // coefficients for row r+1 (from un, loaded last iteration)
        compute_c(un);

        // prefetch row r+2 for next iteration's compute_c
        int rl = r + 2;
        rl = (rl < 0) ? 0 : (rl > MMI - 1 ? MMI - 1 : rl);
        load_row(rl, un);
    }

    // K[255][255] lives in lane 63's kup[2] (j = 4*63+2+1 = 255)
    if (lane == 63) atomicAdd(out, w * kup[2]);
}

extern "C" void kernel_launch(void* const* d_in, const int* in_sizes, int n_in,
                              void* d_out, int out_size, void* d_ws, size_t ws_size,
                              hipStream_t stream) {
    const float* X = (const float*)d_in[0];
    const float* Y = (const float*)d_in[1];
    float* out = (float*)d_out;
    hipMemsetAsync(out, 0, sizeof(float), stream);
    sig_pde<<<dim3(3 * NA), dim3(64), 0, stream>>>(X, Y, out);
}

// Round 4
// 112.507 us; speedup vs baseline: 1.6738x; 1.0275x over previous
//
#include <hip/hip_runtime.h>

typedef float f32x2 __attribute__((ext_vector_type(2)));

#define NA   128   // batches
#define NPTS 256   // points per path
#define DD   16    // feature dim
#define MMI  255   // increments per axis (NPTS-1)
#define NSTEP (MMI + 63)   // 318, divisible by 3

// whole-wave shift-down-by-1 via DPP (lane l gets lane l-1's value).
// Lane 0 (invalid source, bound_ctrl=0) keeps `old` = boundary value.
__device__ __forceinline__ float wave_shr1(float x, float boundary) {
    int r = __builtin_amdgcn_update_dpp(
        __builtin_bit_cast(int, boundary),
        __builtin_bit_cast(int, x),
        0x138 /* wave_shr:1 */, 0xF, 0xF, false);
    return __builtin_bit_cast(float, r);
}

// One wave per (pair, batch) problem. Lane l owns inc-columns 4l..4l+3.
// Skewed wavefront: at step s, lane l processes inc-row r = s - l.
// Row 255 of dU is all-zero: out-of-range rows clamp to it, giving g=0 =>
// c1=c2=1 => recurrence maps the all-ones boundary state to itself, so no
// per-lane masking is needed anywhere.
// LDS row data is triple-buffered in registers (loaded 2 steps ahead).
__global__ __launch_bounds__(64)
void sig_pde(const float* __restrict__ X, const float* __restrict__ Y,
             float* __restrict__ out) {
    const int pid  = blockIdx.x;
    const int pair = pid >> 7;     // 0: XX, 1: YY, 2: XY
    const int a    = pid & 127;
    const float* U = (pair == 1) ? Y : X;
    const float* V = (pair == 0) ? X : Y;
    const float  w = (pair == 2) ? (-2.0f / (float)NA) : (1.0f / (float)NA);
    U += (size_t)a * (NPTS * DD);
    V += (size_t)a * (NPTS * DD);

    // dU[qd][r][0..3] = channels 4qd..4qd+3 of increment row r; row 255 = 0.
    __shared__ float dU[4][256][4];

    const int lane = threadIdx.x;

    // ---- stage dU = diff(U) into LDS (row 255 zeroed) ----
    const float4* U4 = (const float4*)U;
    #pragma unroll
    for (int i = 0; i < 16; ++i) {
        int t  = lane + (i << 6);          // 0..1023
        int qd = t >> 8;
        int r  = t & 255;
        float4 val = make_float4(0.f, 0.f, 0.f, 0.f);
        if (r < MMI) {
            float4 lo = U4[r * 4 + qd];
            float4 hi = U4[r * 4 + 4 + qd];
            val = make_float4(hi.x - lo.x, hi.y - lo.y, hi.z - lo.z, hi.w - lo.w);
        }
        *(float4*)(&dU[qd][r][0]) = val;
    }

    // ---- dV for this lane's 4 columns, registers (zero for col >= 255) ----
    f32x2 v[4][8];
    #pragma unroll
    for (int k = 0; k < 4; ++k) {
        int j = (lane << 2) + k;
        const bool valid = (j < MMI);
        const int jj = valid ? j : 0;
        const float2* Va = (const float2*)(V + (size_t)jj * DD);
        const float2* Vb = (const float2*)(V + (size_t)(jj + 1) * DD);
        #pragma unroll
        for (int q = 0; q < 8; ++q) {
            float2 lo = Va[q], hi = Vb[q];
            v[k][q] = valid ? f32x2{hi.x - lo.x, hi.y - lo.y} : f32x2{0.f, 0.f};
        }
    }

    __syncthreads();

    // row index for step s (clamped to the zero row)
    auto rowidx = [&](int s) {
        int rr = s - lane;
        return ((unsigned)rr < (unsigned)MMI) ? rr : 255;
    };
    auto load_row = [&](int s, f32x2* uu) {
        const float4* p = (const float4*)&dU[0][rowidx(s)][0];
        #pragma unroll
        for (int q = 0; q < 4; ++q) {
            float4 t = p[q << 8];          // offsets 0/4096/8192/12288 bytes
            uu[2 * q + 0] = f32x2{t.x, t.y};
            uu[2 * q + 1] = f32x2{t.z, t.w};
        }
    };

    float c1[4], c2[4];
    auto compute_c = [&](const f32x2* uu) {
        #pragma unroll
        for (int k = 0; k < 4; ++k) {
            f32x2 acc = uu[0] * v[k][0];
            #pragma unroll
            for (int q = 1; q < 8; ++q) acc += uu[q] * v[k][q];  // v_pk_fma_f32
            const float g = acc.x + acc.y;
            const float e = g * g * (1.0f / 12.0f);
            c1[k] = fmaf(0.5f, g, 1.0f) + e;   // 1 + g/2 + g^2/12
            c2[k] = 1.0f - e;                  // 1 - g^2/12
        }
    };

    // kup[k] = K[r+1][4l+k+1] after processing row r
    float kup0 = 1.f, kup1 = 1.f, kup2 = 1.f, kup3 = 1.f;
    float shnew = 1.f, shprev = 1.f;

    // one recurrence step using current c1/c2
    auto step = [&]() {
        const float left   = shnew;
        const float upleft = shprev;
        const float pre0 = fmaf(kup0, c1[0], -(upleft * c2[0]));
        const float pre1 = fmaf(kup1, c1[1], -(kup0 * c2[1]));
        const float pre2 = fmaf(kup2, c1[2], -(kup1 * c2[2]));
        const float pre3 = fmaf(kup3, c1[3], -(kup2 * c2[3]));
        const float t0 = fmaf(left, c1[0], pre0);
        const float t1 = fmaf(t0,   c1[1], pre1);
        const float t2 = fmaf(t1,   c1[2], pre2);
        const float t3 = fmaf(t2,   c1[3], pre3);
        shprev = shnew;
        kup0 = t0; kup1 = t1; kup2 = t2; kup3 = t3;
        shnew = wave_shr1(t3, 1.0f);
    };

    // pipeline prologue: c <- coeffs(row(step 0)); bufA <- row(1); bufB <- row(2)
    f32x2 bufA[8], bufB[8], bufC[8];
    {
        f32x2 t[8];
        load_row(0, t);
        compute_c(t);
    }
    load_row(1, bufA);
    load_row(2, bufB);

    // steady state, 3 steps per iteration (318 = 3 * 106):
    // invariant at top (step s): c = coeffs(step s); bufA = row(s+1); bufB = row(s+2)
    for (int s = 0; s < NSTEP; s += 3) {
        load_row(s + 3, bufC);
        step();
        compute_c(bufA);     // -> c for step s+1 (buffer loaded 2 steps ago)

        load_row(s + 4, bufA);
        step();
        compute_c(bufB);     // -> c for step s+2

        load_row(s + 5, bufB);
        step();
        compute_c(bufC);     // -> c for step s+3
    }

    // K[255][255] lives in lane 63's kup2 (col j = 4*63+2+1 = 255)
    if (lane == 63) atomicAdd(out, w * kup2);
}

extern "C" void kernel_launch(void* const* d_in, const int* in_sizes, int n_in,
                              void* d_out, int out_size, void* d_ws, size_t ws_size,
                              hipStream_t stream) {
    const float* X = (const float*)d_in[0];
    const float* Y = (const float*)d_in[1];
    float* out = (float*)d_out;
    hipMemsetAsync(out, 0, sizeof(float), stream);
    sig_pde<<<dim3(3 * NA), dim3(64), 0, stream>>>(X, Y, out);
}